// Round 9
// baseline (1637.140 us; speedup 1.0000x reference)
//
#include <hip/hip_runtime.h>
#include <hip/hip_fp16.h>
#include <cstdint>
#include <cstddef>

#define SEQ   128
#define BATCH 256
#define HDIM  1024
#define ODIM  128
#define NBLK  256

typedef _Float16 half_t;
typedef _Float16 half8 __attribute__((ext_vector_type(8)));
typedef float    f32x4 __attribute__((ext_vector_type(4)));
typedef unsigned long long u64;

// dynamic LDS: B weights (128 KB) + P reduce (18 KB) + Hs h-out staging (2 KB)
#define LDS_P_OFF    131072
#define LDS_HS_OFF   (LDS_P_OFF + 2 * 64 * 36 * 4)       // 149504
#define LDS_BYTES    (LDS_HS_OFF + 64 * 16 * 2)          // 151552 (<160 KiB)

// ws: 129 fresh h buffers (no stale-cache hazard => no acquire/invalidate
// needed anywhere), then PER-SLICE counters: slot (t, grp, mh) in a private
// 64-B line; producer gate-wave mh fetch_adds its own slot (fan-in 64 per
// line -- R3's proven level; NOT 256 on one line).  128x4x4x64 B = 128 KB.
#define HBUF_BYTES   524288
#define FLAGS_OFF    ((size_t)129 * HBUF_BYTES)          // 67,633,152

__device__ __forceinline__ float sigmoidf_(float z) {
    return 1.0f / (1.0f + __expf(-z));
}
__device__ __forceinline__ float tanhf_(float z) {
    z = fminf(fmaxf(z, -30.0f), 30.0f);
    float e = __expf(2.0f * z);
    return (e - 1.0f) / (e + 1.0f);
}

// Zero the 128 KB counter region every call (correctness must NOT depend on
// the harness's ws re-poison semantics).
__global__ __launch_bounds__(256) void lstm_init(int* __restrict__ flags) {
    flags[blockIdx.x * 256 + threadIdx.x] = 0;
}

// ---------------------------------------------------------------------------
// Persistent LSTM -- R3 skeleton, two dead barriers removed (R9).
// 256 blocks (1/CU via 148 KB LDS) x 512 threads (8 waves, 2/SIMD).
// grp = blk&3 owns rows [64grp,+64); by = blk>>2 owns 16 units x 4 gates
// (weights f16 in LDS).  Waves: kh = w>>2 (K half), mh = w&3 (16-row slice).
// R9 changes vs R3 (everything else BYTE-IDENTICAL, absmax must stay
// 6.103516e-05):
//  1. post-gates barrier removed: storing wave w reads ONLY Hs rows
//     [16w,16w+16) which it wrote itself -> wave-local s_waitcnt lgkmcnt(0).
//  2. post-store block barrier + block-wide publish removed: each gate wave
//     drains ITS OWN stores (vmcnt(0)) then lane0 fetch_adds the per-slice
//     counter (t,grp,mh) -- publish no longer waits the slowest wave's
//     barrier convergence.  Fan-in stays 64/line (proven); adds/line/step
//     unchanged vs R3.
//  3. detect: wave0 sweeps the 4 slice-slots with ONE vector load
//     (slot = lane&3, 16 lanes broadcast per slot; R6's detect pattern),
//     waits all four == 64, then the (kept) release barrier.
// Barriers/step: 2 (P-ready, post-poll) vs R3's 4.
// Pre-registered: if this is null (>=990 us), declare the fan-in-64
// publish->detect chain the practical floor and stop restructuring.
// ---------------------------------------------------------------------------
__global__ __launch_bounds__(512, 2) void lstm_persist(
    const float* __restrict__ x,
    const float* __restrict__ Wfh, const float* __restrict__ Wih,
    const float* __restrict__ Wgh, const float* __restrict__ Woh,
    const float* __restrict__ Wfx, const float* __restrict__ Wix,
    const float* __restrict__ Wgx, const float* __restrict__ Wox,
    const float* __restrict__ bfx, const float* __restrict__ bix,
    const float* __restrict__ bgx, const float* __restrict__ box,
    const float* __restrict__ bfh, const float* __restrict__ bih,
    const float* __restrict__ bgh, const float* __restrict__ boh,
    const float* __restrict__ Wph, const float* __restrict__ bph,
    char* __restrict__ wsbase, float* __restrict__ out)
{
    extern __shared__ char smem[];
    half_t* Bs = (half_t*)smem;
    float*  P  = (float*)(smem + LDS_P_OFF);
    half_t* Hs = (half_t*)(smem + LDS_HS_OFF);
    int* counters = (int*)(wsbase + FLAGS_OFF);

    const int tid  = threadIdx.x;
    const int blk  = blockIdx.x;
    const int grp  = blk & 3;        // batch group (64 rows)
    const int by   = blk >> 2;       // u-tile within group (16 units)
    const int m0   = grp << 6;
    const int u0   = by << 4;

    const int w    = tid >> 6;
    const int lane = tid & 63;
    const int l15  = lane & 15;
    const int q    = lane >> 4;
    const int kh   = w >> 2;         // K half (512)
    const int mh   = w & 3;          // 16-row slice

    // slice-counter address helper: slot (t, grp, mh) = 16 ints (64 B)
    #define SLICE_CNT(tt, mm) \
        (counters + ((((size_t)(tt) * 4 + grp) * 4 + (mm)) * 16))

    // ---- one-time: weight slice fp32 -> f16 into LDS ----
    // slot d: l15=d&15 (unit), q'=(d>>4)&3, g=(d>>6)&3, kk=(d>>8)&15, kh'=d>>12
    // read addr per instr = contiguous 1024 B across (q,l15) -> conflict-free.
    {
        const float* Wh[4] = {Wfh, Wih, Wgh, Woh};
        for (int d = tid; d < 8192; d += 512) {
            const int ul = d & 15, qq = (d >> 4) & 3, g = (d >> 6) & 3;
            const int kk = (d >> 8) & 15, kh2 = d >> 12;
            const float* src = Wh[g] + (size_t)(u0 + ul) * HDIM
                             + kh2 * 512 + kk * 32 + qq * 8;
            const float4 v0 = *(const float4*)src;
            const float4 v1 = *(const float4*)(src + 4);
            half8 hv;
            hv[0] = (half_t)v0.x; hv[1] = (half_t)v0.y;
            hv[2] = (half_t)v0.z; hv[3] = (half_t)v0.w;
            hv[4] = (half_t)v1.x; hv[5] = (half_t)v1.y;
            hv[6] = (half_t)v1.z; hv[7] = (half_t)v1.w;
            *(half8*)(Bs + (size_t)d * 8) = hv;
        }
    }

    // ---- per-lane constants ----
    const int u = u0 + l15;
    const float bf = bfx[u] + bfh[u], bi = bix[u] + bih[u];
    const float bg = bgx[u] + bgh[u], bo = box[u] + boh[u];
    const float wf = Wfx[u], wi = Wix[u], wg = Wgx[u], wo = Wox[u];

    f32x4 creg = {0.f, 0.f, 0.f, 0.f};   // rows 16*mh + 4*q + e (kh==0 waves)

    __syncthreads();   // LDS weights ready

    for (int t = 0; t < SEQ; ++t) {
        const half_t* hin  = (const half_t*)(wsbase + (size_t)t * HBUF_BYTES);
        half_t*       hout = (half_t*)(wsbase + (size_t)(t + 1) * HBUF_BYTES);

        f32x4 acc[4] = {};

        if (t > 0) {
            // Full A preload: 16 b128 loads (h from XCD-L2 / LLC).
            const half_t* abase = hin + (size_t)(m0 + 16 * mh + l15) * HDIM
                                + kh * 512 + q * 8;
            half8 a[16];
#pragma unroll
            for (int kk = 0; kk < 16; ++kk)
                a[kk] = *(const half8*)(abase + kk * 32);
#pragma unroll
            for (int kk = 0; kk < 16; ++kk) {
                half8 bb[4];
#pragma unroll
                for (int g = 0; g < 4; ++g)
                    bb[g] = *(const half8*)(Bs +
                        ((size_t)((kh << 12) + (kk << 8) + (g << 6) + (q << 4) + l15)) * 8);
#pragma unroll
                for (int g = 0; g < 4; ++g)
                    acc[g] = __builtin_amdgcn_mfma_f32_16x16x32_f16(
                        a[kk], bb[g], acc[g], 0, 0, 0);
            }
        }

        // ---- cross-wave K-reduce: kh=1 partials -> LDS P ----
        if (kh == 1) {
#pragma unroll
            for (int g = 0; g < 4; ++g)
                *(f32x4*)&P[(size_t)((mh >> 1) * 64 + (g << 4) + l15) * 36
                            + (mh & 1) * 16 + (q << 2)] = acc[g];
        }
        __syncthreads();   // b1: P ready

        if (kh == 0) {
            const int lr0 = (mh << 4) + (q << 2);     // local row base
            const float4 xv = *(const float4*)&x[t * BATCH + m0 + lr0];
            const int pb = ((mh >> 1) * 64 + l15) * 36 + (mh & 1) * 16 + (q << 2);
            f32x4 zf = acc[0] + *(const f32x4*)&P[pb];
            f32x4 zi = acc[1] + *(const f32x4*)&P[pb + 16 * 36];
            f32x4 zg = acc[2] + *(const f32x4*)&P[pb + 32 * 36];
            f32x4 zo = acc[3] + *(const f32x4*)&P[pb + 48 * 36];
#pragma unroll
            for (int e = 0; e < 4; ++e) {
                const float xe = (e == 0) ? xv.x : (e == 1) ? xv.y
                               : (e == 2) ? xv.z : xv.w;
                const float fg = sigmoidf_(zf[e] + xe * wf + bf);
                const float ig = sigmoidf_(zi[e] + xe * wi + bi);
                const float gg = tanhf_  (zg[e] + xe * wg + bg);
                const float og = sigmoidf_(zo[e] + xe * wo + bo);
                const float cn = gg * ig + creg[e] * fg;
                creg[e] = cn;
                Hs[(lr0 + e) * 16 + l15] = (half_t)(tanhf_(cn) * og);
            }
        }
        // NO block barrier: storing wave w reads ONLY Hs rows [16w,16w+16)
        // which it wrote itself above.  Wave-local LDS drain suffices.
        asm volatile("s_waitcnt lgkmcnt(0)" ::: "memory");

        // ---- coalesced write-through h store: 1 x u64 per thread (sc1) ----
        if (tid < 256) {
            const int lr = tid >> 2, p = tid & 3;
            const u64 v = *(const u64*)&Hs[lr * 16 + p * 4];
            u64* dst = (u64*)(hout + (size_t)(m0 + lr) * HDIM + u0 + p * 4);
            __hip_atomic_store(dst, v, __ATOMIC_RELAXED, __HIP_MEMORY_SCOPE_AGENT);
        }
        // per-WAVE drain + per-slice publish (no block barrier, no block drain)
        asm volatile("s_waitcnt vmcnt(0)" ::: "memory");
        if (kh == 0 && lane == 0)
            __hip_atomic_fetch_add(SLICE_CNT(t, mh), 1,
                                   __ATOMIC_RELAXED, __HIP_MEMORY_SCOPE_AGENT);

        // ---- detect: wave0 sweeps the 4 slice slots (one vector load) ----
        if (w == 0) {
            int* cp = SLICE_CNT(t, 0) + (lane & 3) * 16;  // slot = lane&3
            for (;;) {
                const int v = __hip_atomic_load(cp, __ATOMIC_RELAXED,
                                                __HIP_MEMORY_SCOPE_AGENT);
                if (__all(v == 64)) break;
                __builtin_amdgcn_s_sleep(2);
            }
        }
        asm volatile("" ::: "memory");
        __syncthreads();   // b2: release (also orders Hs/P reuse next step)
    }

    // ---- fused projection + softmax, group-local row = 64*grp + by ----
    const int row = (grp << 6) + by;
    float* sm     = (float*)smem;
    float* hrow   = sm;
    float* psum   = sm + 1024;
    float* logits = sm + 1536;
    const half_t* hf = (const half_t*)(wsbase + (size_t)SEQ * HBUF_BYTES)
                     + ((size_t)row << 10);

    for (int k = tid; k < HDIM; k += 512) hrow[k] = (float)hf[k];
    __syncthreads();

    const int j = tid & 127, qt = tid >> 7;           // K quarter (256)
    const float4* wp = (const float4*)(Wph + (size_t)j * HDIM + qt * 256);
    const float4* hp = (const float4*)(hrow + qt * 256);
    float s = 0.0f;
#pragma unroll 8
    for (int k4 = 0; k4 < 64; ++k4) {
        const float4 wv = wp[k4];
        const float4 hv = hp[k4];
        s += wv.x * hv.x + wv.y * hv.y + wv.z * hv.z + wv.w * hv.w;
    }
    psum[tid] = s;
    __syncthreads();
    if (tid < ODIM)
        logits[tid] = psum[tid] + psum[tid + 128] + psum[tid + 256]
                    + psum[tid + 384] + bph[tid];
    __syncthreads();
    if (tid < ODIM) {
        float mx = -1e30f;
        for (int i = 0; i < ODIM; ++i) mx = fmaxf(mx, logits[i]);
        psum[tid] = __expf(logits[tid] - mx);
    }
    __syncthreads();
    if (tid < ODIM) {
        float ssum = 0.0f;
        for (int i = 0; i < ODIM; ++i) ssum += psum[i];
        out[row * ODIM + tid] = psum[tid] / ssum;
    }
}

// ---------------------------------------------------------------------------
extern "C" void kernel_launch(void* const* d_in, const int* in_sizes, int n_in,
                              void* d_out, int out_size, void* d_ws, size_t ws_size,
                              hipStream_t stream) {
    const float* x   = (const float*)d_in[0];
    const float* Wfx = (const float*)d_in[1];
    const float* bfx = (const float*)d_in[2];
    const float* Wfh = (const float*)d_in[3];
    const float* bfh = (const float*)d_in[4];
    const float* Wix = (const float*)d_in[5];
    const float* bix = (const float*)d_in[6];
    const float* Wih = (const float*)d_in[7];
    const float* bih = (const float*)d_in[8];
    const float* Wgx = (const float*)d_in[9];
    const float* bgx = (const float*)d_in[10];
    const float* Wgh = (const float*)d_in[11];
    const float* bgh = (const float*)d_in[12];
    const float* Wox = (const float*)d_in[13];
    const float* box = (const float*)d_in[14];
    const float* Woh = (const float*)d_in[15];
    const float* boh = (const float*)d_in[16];
    const float* Wph = (const float*)d_in[17];
    const float* bph = (const float*)d_in[18];
    float* outp = (float*)d_out;

    char* ws = (char*)d_ws;
    int* flags = (int*)(ws + FLAGS_OFF);

    lstm_init<<<128, 256, 0, stream>>>(flags);   // zero 128 KB counter region

    (void)hipFuncSetAttribute((const void*)lstm_persist,
                              hipFuncAttributeMaxDynamicSharedMemorySize,
                              LDS_BYTES);

    void* args[] = {
        (void*)&x,
        (void*)&Wfh, (void*)&Wih, (void*)&Wgh, (void*)&Woh,
        (void*)&Wfx, (void*)&Wix, (void*)&Wgx, (void*)&Wox,
        (void*)&bfx, (void*)&bix, (void*)&bgx, (void*)&box,
        (void*)&bfh, (void*)&bih, (void*)&bgh, (void*)&boh,
        (void*)&Wph, (void*)&bph,
        (void*)&ws, (void*)&outp
    };
    (void)hipLaunchCooperativeKernel((const void*)lstm_persist,
                                     dim3(NBLK), dim3(512),
                                     args, LDS_BYTES, stream);
}

// Round 10
// 996.506 us; speedup vs baseline: 1.6429x; 1.6429x over previous
//
#include <hip/hip_runtime.h>
#include <hip/hip_fp16.h>
#include <cstdint>
#include <cstddef>

#define SEQ   128
#define BATCH 256
#define HDIM  1024
#define ODIM  128
#define NBLK  256

typedef _Float16 half_t;
typedef _Float16 half8 __attribute__((ext_vector_type(8)));
typedef float    f32x4 __attribute__((ext_vector_type(4)));
typedef unsigned long long u64;

// dynamic LDS: B weights (128 KB) + P reduce (18 KB) + Hs h-out staging (2 KB)
#define LDS_P_OFF    131072
#define LDS_HS_OFF   (LDS_P_OFF + 2 * 64 * 36 * 4)       // 149504
#define LDS_BYTES    (LDS_HS_OFF + 64 * 16 * 2)          // 151552 (<160 KiB)

// ws: 129 fresh h buffers (no stale-cache hazard => no acquire/invalidate
// needed anywhere), then counters: int cnt[(t*4+grp)*64] -- one 4-B counter
// per (step, group), padded to a private 256-B slot (no false sharing).
#define HBUF_BYTES   524288
#define FLAGS_OFF    ((size_t)129 * HBUF_BYTES)          // 67,633,152

__device__ __forceinline__ float sigmoidf_(float z) {
    return 1.0f / (1.0f + __expf(-z));
}
__device__ __forceinline__ float tanhf_(float z) {
    z = fminf(fmaxf(z, -30.0f), 30.0f);
    float e = __expf(2.0f * z);
    return (e - 1.0f) / (e + 1.0f);
}

// Zero the 128 KB counter array (ws re-poisoned to 0xAA before every call).
__global__ __launch_bounds__(256) void lstm_init(int* __restrict__ flags) {
    flags[blockIdx.x * 256 + threadIdx.x] = 0;
}

// ---------------------------------------------------------------------------
// Persistent LSTM -- FINAL (R3 verbatim; session best 996 us).
// 256 blocks (1/CU via 148 KB LDS) x 512 threads (8 waves, 2/SIMD).
// grp = blk&3 owns batch rows [64*grp, 64*grp+64); by = blk>>2 owns 16
// hidden units x 4 gates; weights f16 in LDS.  Waves: kh = w>>2 (K half) x
// mh = w&3 (16-row quarter).  h is WRITE-THROUGH (agent-scope relaxed
// stores, sc1 -> LLC); per-step publish = per-wave vmcnt(0) + block barrier
// + ONE agent-scope fetch_add on the (group, step) counter; wave0 polls the
// single 4-B counter (broadcast load) with s_sleep(2) backoff.
// SESSION FINDINGS (9 measured variants):
//  - step = ~1.5 us compute + ~6 us handoff = serialized LLC chain
//    {store-drain, publish, detect, A-fill} + 64-producer straggler tail;
//  - hard block-wide lockstep is LOAD-BEARING: per-slice sync (R7/R9),
//    fewer barriers (R6), distributed publish (R4/R5), two-chain
//    pipelining (R2) all regressed 6-90%; busy-wait anti-DVFS probe (R8)
//    falsified the downclock theory (VALUBusy 13->20%, dur unchanged);
//  - counters (HBM 2%, MfmaUtil 12%) show a latency floor, not a
//    throughput roofline; all identified levers measured null/negative.
// c lives in registers. Fresh h buffer per step kills all stale-cache paths.
// ---------------------------------------------------------------------------
__global__ __launch_bounds__(512, 2) void lstm_persist(
    const float* __restrict__ x,
    const float* __restrict__ Wfh, const float* __restrict__ Wih,
    const float* __restrict__ Wgh, const float* __restrict__ Woh,
    const float* __restrict__ Wfx, const float* __restrict__ Wix,
    const float* __restrict__ Wgx, const float* __restrict__ Wox,
    const float* __restrict__ bfx, const float* __restrict__ bix,
    const float* __restrict__ bgx, const float* __restrict__ box,
    const float* __restrict__ bfh, const float* __restrict__ bih,
    const float* __restrict__ bgh, const float* __restrict__ boh,
    const float* __restrict__ Wph, const float* __restrict__ bph,
    char* __restrict__ wsbase, float* __restrict__ out)
{
    extern __shared__ char smem[];
    half_t* Bs = (half_t*)smem;
    float*  P  = (float*)(smem + LDS_P_OFF);
    half_t* Hs = (half_t*)(smem + LDS_HS_OFF);
    int* counters = (int*)(wsbase + FLAGS_OFF);

    const int tid  = threadIdx.x;
    const int blk  = blockIdx.x;
    const int grp  = blk & 3;        // batch group (64 rows)
    const int by   = blk >> 2;       // u-tile within group (16 units)
    const int m0   = grp << 6;
    const int u0   = by << 4;

    const int w    = tid >> 6;
    const int lane = tid & 63;
    const int l15  = lane & 15;
    const int q    = lane >> 4;
    const int kh   = w >> 2;         // K half (512)
    const int mh   = w & 3;          // 16-row quarter

    // ---- one-time: weight slice fp32 -> f16 into LDS ----
    // slot d: l15=d&15 (unit), q'=(d>>4)&3, g=(d>>6)&3, kk=(d>>8)&15, kh'=d>>12
    // read addr per instr = contiguous 1024 B across (q,l15) -> conflict-free.
    {
        const float* Wh[4] = {Wfh, Wih, Wgh, Woh};
        for (int d = tid; d < 8192; d += 512) {
            const int ul = d & 15, qq = (d >> 4) & 3, g = (d >> 6) & 3;
            const int kk = (d >> 8) & 15, kh2 = d >> 12;
            const float* src = Wh[g] + (size_t)(u0 + ul) * HDIM
                             + kh2 * 512 + kk * 32 + qq * 8;
            const float4 v0 = *(const float4*)src;
            const float4 v1 = *(const float4*)(src + 4);
            half8 hv;
            hv[0] = (half_t)v0.x; hv[1] = (half_t)v0.y;
            hv[2] = (half_t)v0.z; hv[3] = (half_t)v0.w;
            hv[4] = (half_t)v1.x; hv[5] = (half_t)v1.y;
            hv[6] = (half_t)v1.z; hv[7] = (half_t)v1.w;
            *(half8*)(Bs + (size_t)d * 8) = hv;
        }
    }

    // ---- per-lane constants ----
    const int u = u0 + l15;
    const float bf = bfx[u] + bfh[u], bi = bix[u] + bih[u];
    const float bg = bgx[u] + bgh[u], bo = box[u] + boh[u];
    const float wf = Wfx[u], wi = Wix[u], wg = Wgx[u], wo = Wox[u];

    f32x4 creg = {0.f, 0.f, 0.f, 0.f};   // rows 16*mh + 4*q + e (kh==0 waves)

    __syncthreads();   // LDS weights ready

    for (int t = 0; t < SEQ; ++t) {
        const half_t* hin  = (const half_t*)(wsbase + (size_t)t * HBUF_BYTES);
        half_t*       hout = (half_t*)(wsbase + (size_t)(t + 1) * HBUF_BYTES);

        f32x4 acc[4] = {};

        if (t > 0) {
            // Full A preload: 16 b128 loads in flight per wave (h from LLC/L2).
            const half_t* abase = hin + (size_t)(m0 + 16 * mh + l15) * HDIM
                                + kh * 512 + q * 8;
            half8 a[16];
#pragma unroll
            for (int kk = 0; kk < 16; ++kk)
                a[kk] = *(const half8*)(abase + kk * 32);
#pragma unroll
            for (int kk = 0; kk < 16; ++kk) {
                half8 bb[4];
#pragma unroll
                for (int g = 0; g < 4; ++g)
                    bb[g] = *(const half8*)(Bs +
                        ((size_t)((kh << 12) + (kk << 8) + (g << 6) + (q << 4) + l15)) * 8);
#pragma unroll
                for (int g = 0; g < 4; ++g)
                    acc[g] = __builtin_amdgcn_mfma_f32_16x16x32_f16(
                        a[kk], bb[g], acc[g], 0, 0, 0);
            }
        }

        // ---- cross-wave K-reduce: kh=1 partials -> LDS P ----
        if (kh == 1) {
#pragma unroll
            for (int g = 0; g < 4; ++g)
                *(f32x4*)&P[(size_t)((mh >> 1) * 64 + (g << 4) + l15) * 36
                            + (mh & 1) * 16 + (q << 2)] = acc[g];
        }
        __syncthreads();

        if (kh == 0) {
            const int lr0 = (mh << 4) + (q << 2);     // local row base
            const float4 xv = *(const float4*)&x[t * BATCH + m0 + lr0];
            const int pb = ((mh >> 1) * 64 + l15) * 36 + (mh & 1) * 16 + (q << 2);
            f32x4 zf = acc[0] + *(const f32x4*)&P[pb];
            f32x4 zi = acc[1] + *(const f32x4*)&P[pb + 16 * 36];
            f32x4 zg = acc[2] + *(const f32x4*)&P[pb + 32 * 36];
            f32x4 zo = acc[3] + *(const f32x4*)&P[pb + 48 * 36];
#pragma unroll
            for (int e = 0; e < 4; ++e) {
                const float xe = (e == 0) ? xv.x : (e == 1) ? xv.y
                               : (e == 2) ? xv.z : xv.w;
                const float fg = sigmoidf_(zf[e] + xe * wf + bf);
                const float ig = sigmoidf_(zi[e] + xe * wi + bi);
                const float gg = tanhf_  (zg[e] + xe * wg + bg);
                const float og = sigmoidf_(zo[e] + xe * wo + bo);
                const float cn = gg * ig + creg[e] * fg;
                creg[e] = cn;
                Hs[(lr0 + e) * 16 + l15] = (half_t)(tanhf_(cn) * og);
            }
        }
        __syncthreads();   // Hs complete

        // ---- coalesced write-through h store: 1 x u64 per thread (sc1) ----
        if (tid < 256) {
            const int lr = tid >> 2, p = tid & 3;
            const u64 v = *(const u64*)&Hs[lr * 16 + p * 4];
            u64* dst = (u64*)(hout + (size_t)(m0 + lr) * HDIM + u0 + p * 4);
            __hip_atomic_store(dst, v, __ATOMIC_RELAXED, __HIP_MEMORY_SCOPE_AGENT);
        }
        asm volatile("s_waitcnt vmcnt(0)" ::: "memory");  // per-wave: h at LLC
        __syncthreads();                                   // all waves drained

        // ---- publish: ONE far-atomic add per block ----
        int* cnt = &counters[(size_t)((t << 2) + grp) << 6];   // 256-B slot
        if (tid == 0)
            __hip_atomic_fetch_add(cnt, 1, __ATOMIC_RELAXED,
                                   __HIP_MEMORY_SCOPE_AGENT);
        // ---- consume: wave0 polls a single 4-B counter (broadcast load) ----
        if (w == 0) {
            for (;;) {
                const int v = __hip_atomic_load(cnt, __ATOMIC_RELAXED,
                                                __HIP_MEMORY_SCOPE_AGENT);
                if (v == 64) break;
                __builtin_amdgcn_s_sleep(2);
            }
        }
        asm volatile("" ::: "memory");
        __syncthreads();
    }

    // ---- fused projection + softmax, group-local row = 64*grp + by ----
    const int row = (grp << 6) + by;
    float* sm     = (float*)smem;
    float* hrow   = sm;
    float* psum   = sm + 1024;
    float* logits = sm + 1536;
    const half_t* hf = (const half_t*)(wsbase + (size_t)SEQ * HBUF_BYTES)
                     + ((size_t)row << 10);

    for (int k = tid; k < HDIM; k += 512) hrow[k] = (float)hf[k];
    __syncthreads();

    const int j = tid & 127, qt = tid >> 7;           // K quarter (256)
    const float4* wp = (const float4*)(Wph + (size_t)j * HDIM + qt * 256);
    const float4* hp = (const float4*)(hrow + qt * 256);
    float s = 0.0f;
#pragma unroll 8
    for (int k4 = 0; k4 < 64; ++k4) {
        const float4 wv = wp[k4];
        const float4 hv = hp[k4];
        s += wv.x * hv.x + wv.y * hv.y + wv.z * hv.z + wv.w * hv.w;
    }
    psum[tid] = s;
    __syncthreads();
    if (tid < ODIM)
        logits[tid] = psum[tid] + psum[tid + 128] + psum[tid + 256]
                    + psum[tid + 384] + bph[tid];
    __syncthreads();
    if (tid < ODIM) {
        float mx = -1e30f;
        for (int i = 0; i < ODIM; ++i) mx = fmaxf(mx, logits[i]);
        psum[tid] = __expf(logits[tid] - mx);
    }
    __syncthreads();
    if (tid < ODIM) {
        float ssum = 0.0f;
        for (int i = 0; i < ODIM; ++i) ssum += psum[i];
        out[row * ODIM + tid] = psum[tid] / ssum;
    }
}

// ---------------------------------------------------------------------------
extern "C" void kernel_launch(void* const* d_in, const int* in_sizes, int n_in,
                              void* d_out, int out_size, void* d_ws, size_t ws_size,
                              hipStream_t stream) {
    const float* x   = (const float*)d_in[0];
    const float* Wfx = (const float*)d_in[1];
    const float* bfx = (const float*)d_in[2];
    const float* Wfh = (const float*)d_in[3];
    const float* bfh = (const float*)d_in[4];
    const float* Wix = (const float*)d_in[5];
    const float* bix = (const float*)d_in[6];
    const float* Wih = (const float*)d_in[7];
    const float* bih = (const float*)d_in[8];
    const float* Wgx = (const float*)d_in[9];
    const float* bgx = (const float*)d_in[10];
    const float* Wgh = (const float*)d_in[11];
    const float* bgh = (const float*)d_in[12];
    const float* Wox = (const float*)d_in[13];
    const float* box = (const float*)d_in[14];
    const float* Woh = (const float*)d_in[15];
    const float* boh = (const float*)d_in[16];
    const float* Wph = (const float*)d_in[17];
    const float* bph = (const float*)d_in[18];
    float* outp = (float*)d_out;

    char* ws = (char*)d_ws;
    int* flags = (int*)(ws + FLAGS_OFF);

    lstm_init<<<128, 256, 0, stream>>>(flags);   // zero 128 KB counter region

    (void)hipFuncSetAttribute((const void*)lstm_persist,
                              hipFuncAttributeMaxDynamicSharedMemorySize,
                              LDS_BYTES);

    void* args[] = {
        (void*)&x,
        (void*)&Wfh, (void*)&Wih, (void*)&Wgh, (void*)&Woh,
        (void*)&Wfx, (void*)&Wix, (void*)&Wgx, (void*)&Wox,
        (void*)&bfx, (void*)&bix, (void*)&bgx, (void*)&box,
        (void*)&bfh, (void*)&bih, (void*)&bgh, (void*)&boh,
        (void*)&Wph, (void*)&bph,
        (void*)&ws, (void*)&outp
    };
    (void)hipLaunchCooperativeKernel((const void*)lstm_persist,
                                     dim3(NBLK), dim3(512),
                                     args, LDS_BYTES, stream);
}